// Round 1
// baseline (196.645 us; speedup 1.0000x reference)
//
#include <hip/hip_runtime.h>

#define NN 16384
#define DD 32
#define BLOCK 256
#define MAXNZ 1024
#define NGRP (BLOCK / DD / 1)   // groups of 32 lanes -> 8

__global__ __launch_bounds__(BLOCK) void sage_kernel(
    const float* __restrict__ A,
    const float* __restrict__ h,
    const float* __restrict__ W,
    float* __restrict__ out)
{
    __shared__ float sW[DD * (DD + 1)];   // padded to kill bank conflicts
    __shared__ int   s_list[MAXNZ];
    __shared__ int   s_cnt;
    __shared__ float s_part[8][DD];
    __shared__ float s_acc[DD];

    const int tid = threadIdx.x;
    const int row = blockIdx.x;

    if (tid == 0) s_cnt = 0;
    // stage W into LDS with +1 padding: sW[r*(DD+1)+c]
    for (int i = tid; i < DD * DD; i += BLOCK) {
        sW[(i / DD) * (DD + 1) + (i % DD)] = W[i];
    }
    __syncthreads();

    // ---- Phase 1: scan row of A for nonzeros (coalesced float4) ----
    const float4* rowA = (const float4*)(A + (size_t)row * NN);
    #pragma unroll 4
    for (int it = 0; it < NN / 4 / BLOCK; ++it) {
        const int idx4 = tid + it * BLOCK;
        float4 v = rowA[idx4];
        if (v.x != 0.f || v.y != 0.f || v.z != 0.f || v.w != 0.f) {
            const int j0 = idx4 * 4;
            if (v.x != 0.f) { int p = atomicAdd(&s_cnt, 1); if (p < MAXNZ) s_list[p] = j0;     }
            if (v.y != 0.f) { int p = atomicAdd(&s_cnt, 1); if (p < MAXNZ) s_list[p] = j0 + 1; }
            if (v.z != 0.f) { int p = atomicAdd(&s_cnt, 1); if (p < MAXNZ) s_list[p] = j0 + 2; }
            if (v.w != 0.f) { int p = atomicAdd(&s_cnt, 1); if (p < MAXNZ) s_list[p] = j0 + 3; }
        }
    }
    __syncthreads();
    const int cnt = min(s_cnt, MAXNZ);

    // ---- Phase 2: gather h rows for the listed neighbors ----
    // 8 groups of 32 lanes; group g handles entries e = g, g+8, ...
    {
        const int grp = tid >> 5;   // 0..7
        const int d   = tid & 31;   // 0..31
        float partial = 0.f;
        for (int e = grp; e < cnt; e += 8) {
            partial += h[(size_t)s_list[e] * DD + d];
        }
        s_part[grp][d] = partial;
    }
    __syncthreads();

    if (tid < DD) {
        float acc = h[(size_t)row * DD + tid];   // + self
        #pragma unroll
        for (int g = 0; g < 8; ++g) acc += s_part[g][tid];
        s_acc[tid] = acc / (float)(cnt + 1);
    }
    __syncthreads();

    // ---- Phase 3: out[row][d] = leaky_relu( sum_k agg[k] * W[d][k] ) ----
    if (tid < DD) {
        float sum = 0.f;
        #pragma unroll
        for (int k = 0; k < DD; ++k) {
            sum += s_acc[k] * sW[tid * (DD + 1) + k];
        }
        out[(size_t)row * DD + tid] = (sum >= 0.f) ? sum : 0.01f * sum;
    }
}

extern "C" void kernel_launch(void* const* d_in, const int* in_sizes, int n_in,
                              void* d_out, int out_size, void* d_ws, size_t ws_size,
                              hipStream_t stream) {
    const float* A = (const float*)d_in[0];   // [N, N]
    const float* h = (const float*)d_in[1];   // [N, D]
    const float* W = (const float*)d_in[2];   // [D, D]
    float* out = (float*)d_out;               // [N, D]

    (void)in_sizes; (void)n_in; (void)out_size; (void)d_ws; (void)ws_size;

    sage_kernel<<<NN, BLOCK, 0, stream>>>(A, h, W, out);
}

// Round 3
// 162.943 us; speedup vs baseline: 1.2068x; 1.2068x over previous
//
#include <hip/hip_runtime.h>

#define NN 16384
#define DD 32
#define BLOCK 256
#define MAXNZ 1024

typedef float vfloat4 __attribute__((ext_vector_type(4)));

__global__ __launch_bounds__(BLOCK) void sage_kernel(
    const float* __restrict__ A,
    const float* __restrict__ h,
    const float* __restrict__ W,
    float* __restrict__ out)
{
    __shared__ float sW[DD * (DD + 1)];   // padded to kill bank conflicts
    __shared__ int   s_list[MAXNZ];
    __shared__ int   s_cnt;
    __shared__ float s_part[8][DD];
    __shared__ float s_acc[DD];

    const int tid = threadIdx.x;
    const int row = blockIdx.x;

    if (tid == 0) s_cnt = 0;
    // stage W into LDS with +1 padding: sW[r*(DD+1)+c]
    for (int i = tid; i < DD * DD; i += BLOCK) {
        sW[(i / DD) * (DD + 1) + (i % DD)] = W[i];
    }
    __syncthreads();

    // ---- Phase 1: scan row of A for nonzeros ----
    // 16 float4 loads/thread, issued 4 at a time for max outstanding VMEM.
    // Nontemporal: A is streamed once (1 GiB), keep it out of L2 so h stays hot.
    const vfloat4* rowA = (const vfloat4*)(A + (size_t)row * NN);

    #pragma unroll
    for (int b = 0; b < 4; ++b) {
        const int i0 = tid + (b * 4 + 0) * BLOCK;
        const int i1 = tid + (b * 4 + 1) * BLOCK;
        const int i2 = tid + (b * 4 + 2) * BLOCK;
        const int i3 = tid + (b * 4 + 3) * BLOCK;
        vfloat4 v0 = __builtin_nontemporal_load(rowA + i0);
        vfloat4 v1 = __builtin_nontemporal_load(rowA + i1);
        vfloat4 v2 = __builtin_nontemporal_load(rowA + i2);
        vfloat4 v3 = __builtin_nontemporal_load(rowA + i3);

        #define PROC(v, idx4)                                                        \
            if ((v)[0] != 0.f || (v)[1] != 0.f || (v)[2] != 0.f || (v)[3] != 0.f) {  \
                const int j0 = (idx4) * 4;                                           \
                if ((v)[0] != 0.f) { int p = atomicAdd(&s_cnt, 1); if (p < MAXNZ) s_list[p] = j0;     } \
                if ((v)[1] != 0.f) { int p = atomicAdd(&s_cnt, 1); if (p < MAXNZ) s_list[p] = j0 + 1; } \
                if ((v)[2] != 0.f) { int p = atomicAdd(&s_cnt, 1); if (p < MAXNZ) s_list[p] = j0 + 2; } \
                if ((v)[3] != 0.f) { int p = atomicAdd(&s_cnt, 1); if (p < MAXNZ) s_list[p] = j0 + 3; } \
            }
        PROC(v0, i0)
        PROC(v1, i1)
        PROC(v2, i2)
        PROC(v3, i3)
        #undef PROC
    }
    __syncthreads();
    const int cnt = min(s_cnt, MAXNZ);

    // ---- Phase 2: gather h rows for the listed neighbors ----
    // 8 groups of 32 lanes; group g handles entries e = g, g+8, ...
    {
        const int grp = tid >> 5;   // 0..7
        const int d   = tid & 31;   // 0..31
        float partial = 0.f;
        for (int e = grp; e < cnt; e += 8) {
            partial += h[(size_t)s_list[e] * DD + d];
        }
        s_part[grp][d] = partial;
    }
    __syncthreads();

    if (tid < DD) {
        float acc = h[(size_t)row * DD + tid];   // + self
        #pragma unroll
        for (int g = 0; g < 8; ++g) acc += s_part[g][tid];
        s_acc[tid] = acc / (float)(cnt + 1);
    }
    __syncthreads();

    // ---- Phase 3: out[row][d] = leaky_relu( sum_k agg[k] * W[d][k] ) ----
    if (tid < DD) {
        float sum = 0.f;
        #pragma unroll
        for (int k = 0; k < DD; ++k) {
            sum += s_acc[k] * sW[tid * (DD + 1) + k];
        }
        out[(size_t)row * DD + tid] = (sum >= 0.f) ? sum : 0.01f * sum;
    }
}

extern "C" void kernel_launch(void* const* d_in, const int* in_sizes, int n_in,
                              void* d_out, int out_size, void* d_ws, size_t ws_size,
                              hipStream_t stream) {
    const float* A = (const float*)d_in[0];   // [N, N]
    const float* h = (const float*)d_in[1];   // [N, D]
    const float* W = (const float*)d_in[2];   // [D, D]
    float* out = (float*)d_out;               // [N, D]

    (void)in_sizes; (void)n_in; (void)out_size; (void)d_ws; (void)ws_size;

    sage_kernel<<<NN, BLOCK, 0, stream>>>(A, h, W, out);
}